// Round 1
// baseline (62.107 us; speedup 1.0000x reference)
//
#include <hip/hip_runtime.h>
#include <math.h>

#define WAVE 64
#define TOPK 16

// One wave per output row. P = number of candidate weights per row (multiple of 64).
// conn row source: rowsel ? conn[rowsel[row]] : conn[row].
// parent: [P_parent_rows, 64] fp32. out: [n, 64] fp32.
template <int P>
__global__ void topk_wm_kernel(const float* __restrict__ conn,
                               const int* __restrict__ rowsel,
                               const float* __restrict__ parent,
                               float* __restrict__ out,
                               int n) {
    const int lane = threadIdx.x & (WAVE - 1);
    const int wave_in_block = threadIdx.x >> 6;
    const int row = blockIdx.x * (blockDim.x >> 6) + wave_in_block;
    if (row >= n) return;

    const long src_row = rowsel ? (long)rowsel[row] : (long)row;
    const float* __restrict__ crow = conn + src_row * (long)P;

    constexpr int VPL = P / WAVE;  // values per lane
    float vals[VPL];
#pragma unroll
    for (int j = 0; j < VPL; ++j) vals[j] = crow[lane + j * WAVE];

    float topv[TOPK];
    int topi[TOPK];

    // 16 rounds of wave-wide arg-max + mask-out.
    for (int t = 0; t < TOPK; ++t) {
        // per-lane local max
        float lm = -INFINITY;
        int li = 0;
#pragma unroll
        for (int j = 0; j < VPL; ++j) {
            if (vals[j] > lm) { lm = vals[j]; li = j; }
        }
        // wave arg-max (value, source lane); ties -> higher lane (matches argsort[-k:] bias)
        float m = lm;
        int srcl = lane;
#pragma unroll
        for (int off = 32; off > 0; off >>= 1) {
            float om = __shfl_xor(m, off);
            int os = __shfl_xor(srcl, off);
            if (om > m || (om == m && os > srcl)) { m = om; srcl = os; }
        }
        // broadcast winner's local slot to reconstruct global index
        int lis = __shfl(li, srcl);
        topv[t] = m;
        topi[t] = srcl + lis * WAVE;
        if (lane == srcl) vals[li] = -INFINITY;  // remove from candidacy
    }

    // softmax over the 16 selected weights (topv[0] is the max)
    const float mx = topv[0];
    float w[TOPK];
    float s = 0.f;
#pragma unroll
    for (int t = 0; t < TOPK; ++t) {
        w[t] = __expf(topv[t] - mx);
        s += w[t];
    }
    const float inv = 1.0f / s;

    // weighted sum of parent rows; lane == output dim (64 dims)
    float acc = 0.f;
#pragma unroll
    for (int t = 0; t < TOPK; ++t) {
        acc += (w[t] * inv) * parent[(long)topi[t] * 64 + lane];
    }
    out[(long)row * 64 + lane] = acc;
}

extern "C" void kernel_launch(void* const* d_in, const int* in_sizes, int n_in,
                              void* d_out, int out_size, void* d_ws, size_t ws_size,
                              hipStream_t stream) {
    const int* ids = (const int*)d_in[0];          // [8192] int32
    const float* conn1 = (const float*)d_in[1];    // [200000, 1024]
    const float* conn2 = (const float*)d_in[2];    // [1024, 256]
    const float* conn3 = (const float*)d_in[3];    // [256, 64]
    const float* root = (const float*)d_in[4];     // [64, 64]
    float* out = (float*)d_out;                    // [8192, 64]

    const int batch = in_sizes[0];                 // 8192
    const int n1 = 1024, n2 = 256;                 // cluster counts

    float* e2 = (float*)d_ws;                      // [256, 64]  = 64 KB
    float* e1 = e2 + (size_t)n2 * 64;              // [1024, 64] = 256 KB

    // 4 waves (256 threads) per block; one wave per row.
    dim3 blk(256);

    // Level 2: conn3 [256, 64] x rootMatrix [64, 64] -> e2 [256, 64]
    topk_wm_kernel<64><<<dim3((n2 + 3) / 4), blk, 0, stream>>>(conn3, nullptr, root, e2, n2);

    // Level 1: conn2 [1024, 256] x e2 -> e1 [1024, 64]
    topk_wm_kernel<256><<<dim3((n1 + 3) / 4), blk, 0, stream>>>(conn2, nullptr, e2, e1, n1);

    // Leaves: conn1[ids] [8192, 1024] x e1 -> out [8192, 64]
    topk_wm_kernel<1024><<<dim3((batch + 3) / 4), blk, 0, stream>>>(conn1, ids, e1, out, batch);
}

// Round 2
// 36.304 us; speedup vs baseline: 1.7108x; 1.7108x over previous
//
#include <hip/hip_runtime.h>
#include <stdint.h>
#include <math.h>

#define WAVE 64
#define TOPK 16

// Monotone bijection fp32 -> uint32 (order-preserving, exact).
__device__ __forceinline__ uint32_t f2s(float f) {
    uint32_t u = __float_as_uint(f);
    return u ^ (uint32_t)(((int32_t)u >> 31) | 0x80000000);
}
__device__ __forceinline__ float s2f(uint32_t s) {
    uint32_t u = (s & 0x80000000u) ? (s ^ 0x80000000u) : ~s;
    return __uint_as_float(u);
}
__device__ __forceinline__ uint32_t umax32(uint32_t a, uint32_t b) { return a > b ? a : b; }

// Wave-wide (64-lane) max of a sortable uint using:
//   4x DPP row_ror (VALU, within rows of 16) + ds_swizzle xor16 + ds_bpermute xor32.
// Only 2 DS ops total. xaddr = (lane ^ 32) * 4, precomputed.
__device__ __forceinline__ uint32_t wave_max64(uint32_t m, int xaddr) {
    uint32_t r;
    r = (uint32_t)__builtin_amdgcn_update_dpp((int)m, (int)m, 0x121, 0xF, 0xF, false); // row_ror:1
    m = umax32(m, r);
    r = (uint32_t)__builtin_amdgcn_update_dpp((int)m, (int)m, 0x122, 0xF, 0xF, false); // row_ror:2
    m = umax32(m, r);
    r = (uint32_t)__builtin_amdgcn_update_dpp((int)m, (int)m, 0x124, 0xF, 0xF, false); // row_ror:4
    m = umax32(m, r);
    r = (uint32_t)__builtin_amdgcn_update_dpp((int)m, (int)m, 0x128, 0xF, 0xF, false); // row_ror:8
    m = umax32(m, r);
    r = (uint32_t)__builtin_amdgcn_ds_swizzle((int)m, 0x401F);                         // xor 16
    m = umax32(m, r);
    r = (uint32_t)__builtin_amdgcn_ds_bpermute(xaddr, (int)m);                         // xor 32
    m = umax32(m, r);
    return m;
}

// One wave per output row. P = candidates per row (multiple of 64).
// conn row: rowsel ? conn[rowsel[row]] : conn[row]. parent: [?, 64] fp32.
template <int P>
__global__ void topk_wm_kernel(const float* __restrict__ conn,
                               const int* __restrict__ rowsel,
                               const float* __restrict__ parent,
                               float* __restrict__ out,
                               int n) {
    const int lane = threadIdx.x & (WAVE - 1);
    const int row = blockIdx.x * (blockDim.x >> 6) + (threadIdx.x >> 6);
    if (row >= n) return;

    const long src_row = rowsel ? (long)rowsel[row] : (long)row;
    const float* __restrict__ crow = conn + src_row * (long)P;

    constexpr int VPL = P / WAVE;  // values per lane
    uint32_t v[VPL];

    // Vectorized coalesced load; layout chosen so global index is recoverable:
    //   VPL>=4: v[c*4+r] = crow[c*256 + lane*4 + r]  -> idx = (j>>2)*256 + lane*4 + (j&3)
    //   VPL==1: v[0]     = crow[lane]                -> idx = lane
    if constexpr (VPL >= 4) {
#pragma unroll
        for (int c = 0; c < VPL / 4; ++c) {
            float4 f4 = *reinterpret_cast<const float4*>(crow + c * (WAVE * 4) + lane * 4);
            v[c * 4 + 0] = f2s(f4.x);
            v[c * 4 + 1] = f2s(f4.y);
            v[c * 4 + 2] = f2s(f4.z);
            v[c * 4 + 3] = f2s(f4.w);
        }
    } else {
        v[0] = f2s(crow[lane]);
    }

    const int xaddr = (lane ^ 32) << 2;

    uint32_t topv[TOPK];  // wave-uniform after each round
    int topi[TOPK];       // wave-uniform global indices

#pragma unroll
    for (int t = 0; t < TOPK; ++t) {
        // per-lane local argmax (static unroll, registers only)
        uint32_t m = v[0];
        int li = 0;
#pragma unroll
        for (int j = 1; j < VPL; ++j) {
            bool c = v[j] > m;
            m = c ? v[j] : m;
            li = c ? j : li;
        }
        const uint32_t m0 = m;
        m = wave_max64(m, xaddr);  // wave max (uniform)

        // winner lane via ballot + scalar clz (no DS); highest lane on ties
        unsigned long long ball = __ballot(m0 == m);
        const int srcl = 63 - __builtin_clzll(ball);
        const int lis = __builtin_amdgcn_readlane(li, srcl);

        topv[t] = m;
        if constexpr (VPL >= 4) {
            topi[t] = (lis >> 2) * (WAVE * 4) + srcl * 4 + (lis & 3);
        } else {
            topi[t] = srcl;
        }

        // clear the winner's slot (static cndmask chain, no dynamic indexing)
        const bool won = (lane == srcl);
#pragma unroll
        for (int j = 0; j < VPL; ++j) {
            if (won && j == lis) v[j] = 0u;
        }
    }

    // softmax over the 16 selected (topv[0] is the max; order-invariant sum)
    const float mx = s2f(topv[0]);
    float w[TOPK];
    float ssum = 0.f;
#pragma unroll
    for (int t = 0; t < TOPK; ++t) {
        w[t] = __expf(s2f(topv[t]) - mx);
        ssum += w[t];
    }
    const float inv = 1.0f / ssum;

    // weighted sum of parent rows; lane == output dim
    float acc = 0.f;
#pragma unroll
    for (int t = 0; t < TOPK; ++t) {
        acc = fmaf(w[t], parent[topi[t] * 64 + lane], acc);
    }
    out[(long)row * 64 + lane] = acc * inv;
}

extern "C" void kernel_launch(void* const* d_in, const int* in_sizes, int n_in,
                              void* d_out, int out_size, void* d_ws, size_t ws_size,
                              hipStream_t stream) {
    const int* ids = (const int*)d_in[0];          // [8192] int32
    const float* conn1 = (const float*)d_in[1];    // [200000, 1024]
    const float* conn2 = (const float*)d_in[2];    // [1024, 256]
    const float* conn3 = (const float*)d_in[3];    // [256, 64]
    const float* root = (const float*)d_in[4];     // [64, 64]
    float* out = (float*)d_out;                    // [8192, 64]

    const int batch = in_sizes[0];                 // 8192
    const int n1 = 1024, n2 = 256;

    float* e2 = (float*)d_ws;                      // [256, 64]
    float* e1 = e2 + (size_t)n2 * 64;              // [1024, 64]

    dim3 blk(256);  // 4 waves/block, one wave per row

    topk_wm_kernel<64><<<dim3(n2 / 4), blk, 0, stream>>>(conn3, nullptr, root, e2, n2);
    topk_wm_kernel<256><<<dim3(n1 / 4), blk, 0, stream>>>(conn2, nullptr, e2, e1, n1);
    topk_wm_kernel<1024><<<dim3(batch / 4), blk, 0, stream>>>(conn1, ids, e1, out, batch);
}

// Round 4
// 33.918 us; speedup vs baseline: 1.8311x; 1.0704x over previous
//
#include <hip/hip_runtime.h>
#include <stdint.h>
#include <math.h>

#define WAVE 64
#define TOPK 16

// Monotone bijection fp32 -> uint32 (order-preserving).
__device__ __forceinline__ uint32_t f2s(float f) {
    uint32_t u = __float_as_uint(f);
    return u ^ (uint32_t)(((int32_t)u >> 31) | 0x80000000u);
}
__device__ __forceinline__ uint32_t umax32(uint32_t a, uint32_t b) { return a > b ? a : b; }
__device__ __forceinline__ uint32_t umin32(uint32_t a, uint32_t b) { return a < b ? a : b; }

template <int CTRL, int RMASK>
__device__ __forceinline__ uint32_t dppmax(uint32_t m) {
    uint32_t r = (uint32_t)__builtin_amdgcn_update_dpp((int)m, (int)m, CTRL, RMASK, 0xF, false);
    return umax32(m, r);
}

// Wave-wide (64-lane) max, pure VALU (DPP) + one readlane. Returns uniform value.
__device__ __forceinline__ uint32_t wave_umax(uint32_t m) {
    m = dppmax<0x121, 0xF>(m);  // row_ror:1
    m = dppmax<0x122, 0xF>(m);  // row_ror:2
    m = dppmax<0x124, 0xF>(m);  // row_ror:4
    m = dppmax<0x128, 0xF>(m);  // row_ror:8  -> row max everywhere
    m = dppmax<0x142, 0xA>(m);  // row_bcast:15 -> rows 1,3
    m = dppmax<0x143, 0xC>(m);  // row_bcast:31 -> rows 2,3; lane 63 = global
    return (uint32_t)__builtin_amdgcn_readlane((int)m, 63);
}

// global position from (local slot j, lane)
template <int VPL>
__device__ __forceinline__ uint32_t gpos(int j, int lane) {
    if constexpr (VPL == 1) return (uint32_t)lane;
    else return (uint32_t)((j >> 2) * (WAVE * 4) + lane * 4 + (j & 3));
}

// One wave per output row. Fast path: quantized-unique keys
// qkey = (f2s(v) & ~(P-1)) | global_pos  (total order, ties -> higher index,
// matching stable argsort[-k:]). Boundary ambiguity (17th key shares quantized
// prefix with 16th) triggers an exact lexicographic fallback.
template <int P>
__global__ void topk_wm_kernel(const float* __restrict__ conn,
                               const int* __restrict__ rowsel,
                               const float* __restrict__ parent,
                               float* __restrict__ out,
                               int n) {
    constexpr int VPL = P / WAVE;
    constexpr uint32_t IMASK = (uint32_t)(P - 1);
    const int lane = threadIdx.x & (WAVE - 1);
    const int row = blockIdx.x * (blockDim.x >> 6) + (threadIdx.x >> 6);
    if (row >= n) return;

    const long src_row = rowsel ? (long)rowsel[row] : (long)row;
    const float* __restrict__ crow = conn + src_row * (long)P;

    uint32_t k[VPL];
    if constexpr (VPL == 1) {
        k[0] = (f2s(crow[lane]) & ~IMASK) | (uint32_t)lane;
    } else {
#pragma unroll
        for (int c = 0; c < VPL / 4; ++c) {
            float4 f4 = *reinterpret_cast<const float4*>(crow + c * (WAVE * 4) + lane * 4);
            const uint32_t b = (uint32_t)(c * (WAVE * 4) + lane * 4);
            k[c * 4 + 0] = (f2s(f4.x) & ~IMASK) | (b + 0u);
            k[c * 4 + 1] = (f2s(f4.y) & ~IMASK) | (b + 1u);
            k[c * 4 + 2] = (f2s(f4.z) & ~IMASK) | (b + 2u);
            k[c * 4 + 3] = (f2s(f4.w) & ~IMASK) | (b + 3u);
        }
        // bitonic sort, descending, key-only (all indices compile-time)
#pragma unroll
        for (int size = 2; size <= VPL; size <<= 1) {
#pragma unroll
            for (int stride = size >> 1; stride > 0; stride >>= 1) {
#pragma unroll
                for (int i = 0; i < VPL; ++i) {
                    const int j = i ^ stride;
                    if (j > i) {
                        const uint32_t a = k[i], b2 = k[j];
                        const uint32_t hi = umax32(a, b2), lo = umin32(a, b2);
                        if ((i & size) == 0) { k[i] = hi; k[j] = lo; }
                        else                 { k[i] = lo; k[j] = hi; }
                    }
                }
            }
        }
    }

    // 16 rounds: wave max of sorted heads; winner shifts its list.
    uint32_t idx[TOPK];
    uint32_t q16 = 0;
#pragma unroll
    for (int t = 0; t < TOPK; ++t) {
        const uint32_t K = wave_umax(k[0]);
        idx[t] = K & IMASK;
        if (t == TOPK - 1) q16 = K & ~IMASK;
        const bool won = (k[0] == K);   // unique keys -> exactly one lane
#pragma unroll
        for (int j = 0; j < VPL - 1; ++j) k[j] = won ? k[j + 1] : k[j];
        k[VPL - 1] = won ? 0u : k[VPL - 1];
    }
    const uint32_t k17 = wave_umax(k[0]);  // largest remaining

    // Ambiguity: only if the 17th shares the quantized prefix with the 16th
    // can the exact top-16 set differ from the quantized one.
    if ((k17 & ~IMASK) == q16) {
        // EXACT fallback (rare, ~1e-3 of rows): lexicographic (value, index).
        uint32_t v[VPL];
        if constexpr (VPL == 1) {
            v[0] = f2s(crow[lane]);
        } else {
#pragma unroll
            for (int c = 0; c < VPL / 4; ++c) {
                float4 f4 = *reinterpret_cast<const float4*>(crow + c * (WAVE * 4) + lane * 4);
                v[c * 4 + 0] = f2s(f4.x);
                v[c * 4 + 1] = f2s(f4.y);
                v[c * 4 + 2] = f2s(f4.z);
                v[c * 4 + 3] = f2s(f4.w);
            }
        }
#pragma unroll
        for (int t = 0; t < TOPK; ++t) {
            uint32_t m = v[0];
            int li = 0;
#pragma unroll
            for (int j = 1; j < VPL; ++j) {
                bool c = v[j] >= m;            // ties -> higher slot (higher index)
                m = c ? v[j] : m;
                li = c ? j : li;
            }
            uint32_t gi = gpos<VPL>(li, lane);
            const uint32_t mygi = gi;
            uint32_t mm = m;
#pragma unroll
            for (int off = 32; off > 0; off >>= 1) {
                uint32_t om = (uint32_t)__shfl_xor((int)mm, off);
                uint32_t og = (uint32_t)__shfl_xor((int)gi, off);
                bool c = (om > mm) || (om == mm && og > gi);
                mm = c ? om : mm;
                gi = c ? og : gi;
            }
            idx[t] = gi;                        // uniform
            const bool won = (mygi == gi) && (m == mm);
#pragma unroll
            for (int j = 0; j < VPL; ++j) {
                if (won && j == li) v[j] = 0u;
            }
        }
    }

    // Epilogue: exact values re-read (L1-hot, wave-uniform), softmax, gather.
    float vsel[TOPK];
#pragma unroll
    for (int t = 0; t < TOPK; ++t) vsel[t] = crow[idx[t]];
    const float v0 = vsel[0];  // within 16 ulp of true max (or exact in fallback)
    float ssum = 0.f, acc = 0.f;
#pragma unroll
    for (int t = 0; t < TOPK; ++t) {
        const float w = __expf(vsel[t] - v0);
        ssum += w;
        acc = fmaf(w, parent[idx[t] * 64u + (uint32_t)lane], acc);
    }
    out[(long)row * 64 + lane] = acc / ssum;
}

extern "C" void kernel_launch(void* const* d_in, const int* in_sizes, int n_in,
                              void* d_out, int out_size, void* d_ws, size_t ws_size,
                              hipStream_t stream) {
    const int* ids = (const int*)d_in[0];          // [8192] int32
    const float* conn1 = (const float*)d_in[1];    // [200000, 1024]
    const float* conn2 = (const float*)d_in[2];    // [1024, 256]
    const float* conn3 = (const float*)d_in[3];    // [256, 64]
    const float* root = (const float*)d_in[4];     // [64, 64]
    float* out = (float*)d_out;                    // [8192, 64]

    const int batch = in_sizes[0];                 // 8192
    const int n1 = 1024, n2 = 256;

    float* e2 = (float*)d_ws;                      // [256, 64]
    float* e1 = e2 + (size_t)n2 * 64;              // [1024, 64]

    dim3 blk(256);  // 4 waves/block, one wave per row

    topk_wm_kernel<64><<<dim3(n2 / 4), blk, 0, stream>>>(conn3, nullptr, root, e2, n2);
    topk_wm_kernel<256><<<dim3(n1 / 4), blk, 0, stream>>>(conn2, nullptr, e2, e1, n1);
    topk_wm_kernel<1024><<<dim3(batch / 4), blk, 0, stream>>>(conn1, ids, e1, out, batch);
}